// Round 6
// baseline (1078.996 us; speedup 1.0000x reference)
//
#include <hip/hip_runtime.h>

#define N_NODES 100000
#define N_EDGES 1600000
#define N_GRAPHS_C 64
#define IN_F 86
#define H 64
#define N_BKT 391            // ceil(100000/256), bucket = dst >> 8
#define SC_EPT 8             // edges per thread in bucket passes
#define SC_TILE 2048         // 256 threads * 8
#define SC_GRID 782          // ceil(1.6M / 2048)
#define BC_GRID 860          // bn+count grid: 860*256 = 220160, divisible by 86
typedef unsigned short ushort;

__device__ inline float bf2f(ushort u) { return __uint_as_float(((unsigned)u) << 16); }
__device__ inline ushort f2bf(float f) {
    unsigned x = __float_as_uint(f);
    return (ushort)((x + 0x7fffu + ((x >> 16) & 1u)) >> 16);  // RNE
}

// ---------------- fused: BN stats + per-bucket edge counts ----------------
__global__ void bn_count_k(const float* __restrict__ x, const int* __restrict__ dst,
                           float* __restrict__ bnsum, float* __restrict__ bnsq,
                           int* __restrict__ bcnt) {
    __shared__ float s1[IN_F], s2[IN_F];
    __shared__ int hist[N_BKT];
    int tid = threadIdx.x;
    if (tid < IN_F) { s1[tid] = 0.f; s2[tid] = 0.f; }
    for (int i = tid; i < N_BKT; i += 256) hist[i] = 0;
    __syncthreads();
    // edge histogram (blocks < SC_GRID)
    if (blockIdx.x < SC_GRID) {
        int e0 = blockIdx.x * SC_TILE;
#pragma unroll
        for (int i = 0; i < SC_EPT; i++) {
            int e = e0 + i * 256 + tid;
            if (e < N_EDGES) atomicAdd(&hist[dst[e] >> 8], 1);
        }
    }
    // bn partial sums: T divisible by 86 -> f invariant per thread
    const int T = BC_GRID * 256;
    int t = blockIdx.x * 256 + tid;
    float sum = 0.f, sq = 0.f;
    for (int idx = t; idx < N_NODES * IN_F; idx += T) {
        float v = x[idx];
        sum += v; sq += v * v;
    }
    int f = t % IN_F;
    atomicAdd(&s1[f], sum);
    atomicAdd(&s2[f], sq);
    __syncthreads();
    if (tid < IN_F) {
        atomicAdd(&bnsum[tid], s1[tid]);
        atomicAdd(&bnsq[tid], s2[tid]);
    }
    if (blockIdx.x < SC_GRID)
        for (int i = tid; i < N_BKT; i += 256) atomicAdd(&bcnt[i], hist[i]);
}

// ---------------- fused: bucket scan + BN-fold prep ----------------
__global__ void scanprep_k(const int* __restrict__ bcnt, int* __restrict__ bstart,
                           int* __restrict__ gcursor,
                           const float* __restrict__ bnsum, const float* __restrict__ bnsq,
                           const float* __restrict__ gamma, const float* __restrict__ beta,
                           const float* __restrict__ W1, const float* __restrict__ b1,
                           float* __restrict__ W1p, float* __restrict__ c1) {
    __shared__ int tmp[512];
    __shared__ float scale[IN_F], shift[IN_F];
    int t = threadIdx.x;
    int v = (t < N_BKT) ? bcnt[t] : 0;
    tmp[t] = v;
    __syncthreads();
    for (int off = 1; off < 512; off <<= 1) {
        int a = (t >= off) ? tmp[t - off] : 0;
        __syncthreads();
        tmp[t] += a;
        __syncthreads();
    }
    if (t < N_BKT) { bstart[t] = tmp[t] - v; gcursor[t] = tmp[t] - v; }
    if (t == N_BKT - 1) bstart[N_BKT] = tmp[t];
    // BN fold
    if (t < IN_F) {
        float mean = bnsum[t] * (1.0f / N_NODES);
        float var  = bnsq[t] * (1.0f / N_NODES) - mean * mean;
        float sc = gamma[t] * rsqrtf(var + 1e-5f);
        scale[t] = sc;
        shift[t] = beta[t] - mean * sc;
    }
    __syncthreads();
    for (int idx = t; idx < IN_F * H; idx += 512) W1p[idx] = scale[idx / H] * W1[idx];
    if (t < H) {
        float acc = b1[t];
        for (int i = 0; i < IN_F; i++) acc += shift[i] * W1[i * H + t];
        c1[t] = acc;
    }
}

// ---------------- CSR pass 1: partition edges (packed (src<<8)|dstLow) ----------------
__global__ void bucket_scatter_k(const int* __restrict__ src, const int* __restrict__ dst,
                                 int* __restrict__ gcursor, unsigned* __restrict__ ebkt) {
    __shared__ int hist[N_BKT];
    __shared__ int base[N_BKT];
    int tid = threadIdx.x;
    for (int i = tid; i < N_BKT; i += 256) hist[i] = 0;
    __syncthreads();
    int e0 = blockIdx.x * SC_TILE;
    unsigned pk[SC_EPT];
    int bk[SC_EPT], lo[SC_EPT];
#pragma unroll
    for (int i = 0; i < SC_EPT; i++) {
        int e = e0 + i * 256 + tid;
        if (e < N_EDGES) {
            int d = dst[e];
            pk[i] = ((unsigned)src[e] << 8) | (unsigned)(d & 255);
            bk[i] = d >> 8;
            lo[i] = atomicAdd(&hist[bk[i]], 1);
        }
    }
    __syncthreads();
    for (int i = tid; i < N_BKT; i += 256) base[i] = atomicAdd(&gcursor[i], hist[i]);
    __syncthreads();
#pragma unroll
    for (int i = 0; i < SC_EPT; i++) {
        int e = e0 + i * 256 + tid;
        if (e < N_EDGES) ebkt[base[bk[i]] + lo[i]] = pk[i];
    }
}

// ---------------- CSR pass 2: per-bucket degree+scan+fill ----------------
// rs[n] = INCLUSIVE end of node n's csr row.
__global__ void bucket_fill_k(const unsigned* __restrict__ ebkt, const int* __restrict__ bstart,
                              int* __restrict__ rs, int* __restrict__ csr) {
    __shared__ int deg[256];
    __shared__ int scn[256];
    __shared__ int cur[256];
    int b = blockIdx.x;
    int tid = threadIdx.x;
    int e0 = bstart[b], e1 = bstart[b + 1];
    deg[tid] = 0;
    __syncthreads();
    for (int e = e0 + tid; e < e1; e += 256) atomicAdd(&deg[ebkt[e] & 255u], 1);
    __syncthreads();
    scn[tid] = deg[tid];
    __syncthreads();
    for (int off = 1; off < 256; off <<= 1) {
        int a = (tid >= off) ? scn[tid - off] : 0;
        __syncthreads();
        scn[tid] += a;
        __syncthreads();
    }
    int node = (b << 8) + tid;
    if (node < N_NODES) rs[node] = e0 + scn[tid];
    cur[tid] = e0 + scn[tid] - deg[tid];
    __syncthreads();
    for (int e = e0 + tid; e < e1; e += 256) {
        unsigned p = ebkt[e];
        int pos = atomicAdd(&cur[p & 255u], 1);
        csr[pos] = (int)(p >> 8);
    }
}

// ---------------- GEMM (f32 in, K=86): Ybf16 = X @ W + bias ----------------
__global__ __launch_bounds__(256) void gemm_f32_k(const float* __restrict__ X,
                                                  const float* __restrict__ W,
                                                  const float* __restrict__ bias,
                                                  ushort* __restrict__ Y, int N) {
    const int K = IN_F;
    __shared__ __align__(16) float Xl[64][IN_F + 1];
    __shared__ __align__(16) float Wl[IN_F][64];
    int tid = threadIdx.x;
    int row0 = blockIdx.x * 64;
    for (int i = tid; i < K * 64; i += 256) Wl[i / 64][i % 64] = W[i];
    for (int i = tid; i < 64 * K; i += 256) {
        int r = i / K, c = i % K;
        Xl[r][c] = (row0 + r < N) ? X[(size_t)(row0 + r) * K + c] : 0.f;
    }
    __syncthreads();
    int cg = tid & 15, rg = tid >> 4;
    float4 b4 = *(const float4*)&bias[cg * 4];
    float acc[4][4];
    for (int i = 0; i < 4; i++) { acc[i][0] = b4.x; acc[i][1] = b4.y; acc[i][2] = b4.z; acc[i][3] = b4.w; }
    for (int k = 0; k < K; k++) {
        float4 w = *(const float4*)&Wl[k][cg * 4];
        float x0 = Xl[rg * 4 + 0][k];
        float x1 = Xl[rg * 4 + 1][k];
        float x2 = Xl[rg * 4 + 2][k];
        float x3 = Xl[rg * 4 + 3][k];
        acc[0][0] += x0 * w.x; acc[0][1] += x0 * w.y; acc[0][2] += x0 * w.z; acc[0][3] += x0 * w.w;
        acc[1][0] += x1 * w.x; acc[1][1] += x1 * w.y; acc[1][2] += x1 * w.z; acc[1][3] += x1 * w.w;
        acc[2][0] += x2 * w.x; acc[2][1] += x2 * w.y; acc[2][2] += x2 * w.z; acc[2][3] += x2 * w.w;
        acc[3][0] += x3 * w.x; acc[3][1] += x3 * w.y; acc[3][2] += x3 * w.z; acc[3][3] += x3 * w.w;
    }
    for (int i = 0; i < 4; i++) {
        int gr = row0 + rg * 4 + i;
        if (gr < N) {
            ushort4 o;
            o.x = f2bf(acc[i][0]); o.y = f2bf(acc[i][1]);
            o.z = f2bf(acc[i][2]); o.w = f2bf(acc[i][3]);
            *(ushort4*)&Y[(size_t)gr * 64 + cg * 4] = o;
        }
    }
}

// ---------------- GEMM (bf16 in, K=64): Ybf16 = X @ W + bias ----------------
__global__ __launch_bounds__(256) void gemm_bf16_k(const ushort* __restrict__ X,
                                                   const float* __restrict__ W,
                                                   const float* __restrict__ bias,
                                                   ushort* __restrict__ Y, int N) {
    const int K = H;
    __shared__ __align__(16) float Xl[64][H + 1];
    __shared__ __align__(16) float Wl[H][64];
    int tid = threadIdx.x;
    int row0 = blockIdx.x * 64;
    for (int i = tid; i < K * 64; i += 256) Wl[i / 64][i % 64] = W[i];
    // 64 rows x 16 ushort4 each
    for (int i = tid; i < 64 * 16; i += 256) {
        int r = i >> 4, c4 = (i & 15) * 4;
        if (row0 + r < N) {
            ushort4 u = *(const ushort4*)&X[(size_t)(row0 + r) * K + c4];
            Xl[r][c4 + 0] = bf2f(u.x); Xl[r][c4 + 1] = bf2f(u.y);
            Xl[r][c4 + 2] = bf2f(u.z); Xl[r][c4 + 3] = bf2f(u.w);
        } else {
            Xl[r][c4 + 0] = 0.f; Xl[r][c4 + 1] = 0.f;
            Xl[r][c4 + 2] = 0.f; Xl[r][c4 + 3] = 0.f;
        }
    }
    __syncthreads();
    int cg = tid & 15, rg = tid >> 4;
    float4 b4 = *(const float4*)&bias[cg * 4];
    float acc[4][4];
    for (int i = 0; i < 4; i++) { acc[i][0] = b4.x; acc[i][1] = b4.y; acc[i][2] = b4.z; acc[i][3] = b4.w; }
    for (int k = 0; k < K; k++) {
        float4 w = *(const float4*)&Wl[k][cg * 4];
        float x0 = Xl[rg * 4 + 0][k];
        float x1 = Xl[rg * 4 + 1][k];
        float x2 = Xl[rg * 4 + 2][k];
        float x3 = Xl[rg * 4 + 3][k];
        acc[0][0] += x0 * w.x; acc[0][1] += x0 * w.y; acc[0][2] += x0 * w.z; acc[0][3] += x0 * w.w;
        acc[1][0] += x1 * w.x; acc[1][1] += x1 * w.y; acc[1][2] += x1 * w.z; acc[1][3] += x1 * w.w;
        acc[2][0] += x2 * w.x; acc[2][1] += x2 * w.y; acc[2][2] += x2 * w.z; acc[2][3] += x2 * w.w;
        acc[3][0] += x3 * w.x; acc[3][1] += x3 * w.y; acc[3][2] += x3 * w.z; acc[3][3] += x3 * w.w;
    }
    for (int i = 0; i < 4; i++) {
        int gr = row0 + rg * 4 + i;
        if (gr < N) {
            ushort4 o;
            o.x = f2bf(acc[i][0]); o.y = f2bf(acc[i][1]);
            o.z = f2bf(acc[i][2]); o.w = f2bf(acc[i][3]);
            *(ushort4*)&Y[(size_t)gr * 64 + cg * 4] = o;
        }
    }
}

// ---------------- gather core: 8-deep unrolled mean-aggregate ----------------
__device__ inline float gather_row(const ushort* __restrict__ g, const int* __restrict__ csr,
                                   int start, int end, int lane) {
    float a0 = 0.f, a1 = 0.f, a2 = 0.f, a3 = 0.f;
    float a4 = 0.f, a5 = 0.f, a6 = 0.f, a7 = 0.f;
    for (int j0 = start; j0 < end; j0 += 64) {
        int cnt = min(64, end - j0);
        int myidx = (lane < cnt) ? csr[j0 + lane] : 0;
        int j = 0;
        for (; j + 7 < cnt; j += 8) {
            int s0 = __shfl(myidx, j, 64);
            int s1 = __shfl(myidx, j + 1, 64);
            int s2 = __shfl(myidx, j + 2, 64);
            int s3 = __shfl(myidx, j + 3, 64);
            int s4 = __shfl(myidx, j + 4, 64);
            int s5 = __shfl(myidx, j + 5, 64);
            int s6 = __shfl(myidx, j + 6, 64);
            int s7 = __shfl(myidx, j + 7, 64);
            a0 += bf2f(g[(size_t)s0 * H + lane]);
            a1 += bf2f(g[(size_t)s1 * H + lane]);
            a2 += bf2f(g[(size_t)s2 * H + lane]);
            a3 += bf2f(g[(size_t)s3 * H + lane]);
            a4 += bf2f(g[(size_t)s4 * H + lane]);
            a5 += bf2f(g[(size_t)s5 * H + lane]);
            a6 += bf2f(g[(size_t)s6 * H + lane]);
            a7 += bf2f(g[(size_t)s7 * H + lane]);
        }
        for (; j + 3 < cnt; j += 4) {
            int s0 = __shfl(myidx, j, 64);
            int s1 = __shfl(myidx, j + 1, 64);
            int s2 = __shfl(myidx, j + 2, 64);
            int s3 = __shfl(myidx, j + 3, 64);
            a0 += bf2f(g[(size_t)s0 * H + lane]);
            a1 += bf2f(g[(size_t)s1 * H + lane]);
            a2 += bf2f(g[(size_t)s2 * H + lane]);
            a3 += bf2f(g[(size_t)s3 * H + lane]);
        }
        for (; j < cnt; j++) {
            int s = __shfl(myidx, j, 64);
            a0 += bf2f(g[(size_t)s * H + lane]);
        }
    }
    return ((a0 + a1) + (a2 + a3)) + ((a4 + a5) + (a6 + a7));
}

// ---------------- gather1: h1[n] = relu(mean in-nbr g or g[n]) -> bf16 ----------------
__global__ void gather1_k(const ushort* __restrict__ g, const int* __restrict__ rs,
                          const int* __restrict__ csr, ushort* __restrict__ out) {
    int lane = threadIdx.x & 63;
    int n = blockIdx.x * 4 + (threadIdx.x >> 6);
    if (n >= N_NODES) return;
    int start = (n == 0) ? 0 : rs[n - 1];
    int end = rs[n];
    float acc = gather_row(g, csr, start, end, lane);
    int d = end - start;
    float val = (d > 0) ? acc / (float)d : bf2f(g[(size_t)n * H + lane]);
    out[(size_t)n * H + lane] = f2bf(fmaxf(val, 0.f));
}

// ---------------- gather2 + pool: relu'd row atomically into gsum[graph] ----------------
__global__ void gather2_pool_k(const ushort* __restrict__ g, const int* __restrict__ rs,
                               const int* __restrict__ csr, const int* __restrict__ gid,
                               float* __restrict__ gsum, int* __restrict__ gcnt) {
    int lane = threadIdx.x & 63;
    int n = blockIdx.x * 4 + (threadIdx.x >> 6);
    if (n >= N_NODES) return;
    int start = (n == 0) ? 0 : rs[n - 1];
    int end = rs[n];
    float acc = gather_row(g, csr, start, end, lane);
    int d = end - start;
    float val = (d > 0) ? acc / (float)d : bf2f(g[(size_t)n * H + lane]);
    val = fmaxf(val, 0.f);
    int gg = gid[n];
    atomicAdd(&gsum[gg * H + lane], val);
    if (lane == 0) atomicAdd(&gcnt[gg], 1);
}

// ---------------- FC head + sigmoid (weights staged in LDS) ----------------
__global__ void head_k(const float* __restrict__ gsum, const int* __restrict__ gcnt,
                       const float* __restrict__ fc1w, const float* __restrict__ fc1b,
                       const float* __restrict__ fc2w, const float* __restrict__ fc2b,
                       float* __restrict__ out) {
    __shared__ float w1[H * 32];
    __shared__ float w2[32], bb1[32];
    int b = threadIdx.x;
    for (int i = b; i < H * 32; i += 64) w1[i] = fc1w[i];
    if (b < 32) { w2[b] = fc2w[b]; bb1[b] = fc1b[b]; }
    __syncthreads();
    if (b >= N_GRAPHS_C) return;
    float hg[H];
    float inv = 1.0f / fmaxf((float)gcnt[b], 1.0f);
    for (int k = 0; k < H; k++) hg[k] = gsum[b * H + k] * inv;
    float z = fc2b[0];
    for (int j = 0; j < 32; j++) {
        float t = bb1[j];
        for (int k = 0; k < H; k++) t += hg[k] * w1[k * 32 + j];
        z += t * w2[j];
    }
    out[b] = 1.0f / (1.0f + expf(-z));
}

extern "C" void kernel_launch(void* const* d_in, const int* in_sizes, int n_in,
                              void* d_out, int out_size, void* d_ws, size_t ws_size,
                              hipStream_t stream) {
    const float* x        = (const float*)d_in[0];
    const int*   edge_src = (const int*)d_in[1];
    const int*   edge_dst = (const int*)d_in[2];
    const int*   gid      = (const int*)d_in[3];
    const float* bn_gamma = (const float*)d_in[5];
    const float* bn_beta  = (const float*)d_in[6];
    const float* W1       = (const float*)d_in[7];
    const float* b1       = (const float*)d_in[8];
    const float* W2       = (const float*)d_in[9];
    const float* b2       = (const float*)d_in[10];
    const float* fc1w     = (const float*)d_in[11];
    const float* fc1b     = (const float*)d_in[12];
    const float* fc2w     = (const float*)d_in[13];
    const float* fc2b     = (const float*)d_in[14];
    float* out = (float*)d_out;

    // ---- workspace layout ----
    char* ws = (char*)d_ws;
    size_t off = 0;
    auto alloc = [&](size_t bytes) { void* p = ws + off; off += (bytes + 255) & ~(size_t)255; return p; };
    // zero-region: bnsum[86] bnsq[86] bcnt[391] gsum[4096] gcnt[64]  (contiguous, one memset)
    const size_t ZW = IN_F + IN_F + N_BKT + N_GRAPHS_C * H + N_GRAPHS_C;
    float* zreg  = (float*)alloc(ZW * sizeof(float));
    float* bnsum = zreg;
    float* bnsq  = bnsum + IN_F;
    int*   bcnt  = (int*)(bnsq + IN_F);
    float* gsum  = (float*)(bcnt + N_BKT);
    int*   gcnt  = (int*)(gsum + N_GRAPHS_C * H);
    float* W1p     = (float*)alloc(IN_F * H * sizeof(float));
    float* c1      = (float*)alloc(H * sizeof(float));
    int*   bstart  = (int*)alloc((N_BKT + 1) * sizeof(int));
    int*   gcursor = (int*)alloc(N_BKT * sizeof(int));
    int*   rs      = (int*)alloc(N_NODES * sizeof(int));
    int*   csr     = (int*)alloc((size_t)N_EDGES * sizeof(int));
    ushort* gbuf   = (ushort*)alloc((size_t)N_NODES * H * sizeof(ushort));  // bf16 g1/g2 (12.8 MB)
    ushort* h1     = (ushort*)alloc((size_t)N_NODES * H * sizeof(ushort));  // bf16 h1  (12.8 MB)
    // ebkt (6.4 MB packed) aliases gbuf: consumed by bucket_fill_k BEFORE gemm writes gbuf.
    unsigned* ebkt = (unsigned*)gbuf;

    hipMemsetAsync(zreg, 0, ZW * sizeof(float), stream);

    // ---- fused BN stats + bucket counts ----
    bn_count_k<<<BC_GRID, 256, 0, stream>>>(x, edge_dst, bnsum, bnsq, bcnt);
    // ---- fused bucket scan + BN fold ----
    scanprep_k<<<1, 512, 0, stream>>>(bcnt, bstart, gcursor, bnsum, bnsq,
                                      bn_gamma, bn_beta, W1, b1, W1p, c1);
    // ---- CSR build ----
    bucket_scatter_k<<<SC_GRID, 256, 0, stream>>>(edge_src, edge_dst, gcursor, ebkt);
    bucket_fill_k<<<N_BKT, 256, 0, stream>>>(ebkt, bstart, rs, csr);

    // ---- layer 1 ----
    gemm_f32_k<<<(N_NODES + 63) / 64, 256, 0, stream>>>(x, W1p, c1, gbuf, N_NODES);
    gather1_k<<<(N_NODES + 3) / 4, 256, 0, stream>>>(gbuf, rs, csr, h1);

    // ---- layer 2 ----
    gemm_bf16_k<<<(N_NODES + 63) / 64, 256, 0, stream>>>(h1, W2, b2, gbuf, N_NODES);
    gather2_pool_k<<<(N_NODES + 3) / 4, 256, 0, stream>>>(gbuf, rs, csr, gid, gsum, gcnt);

    // ---- head ----
    head_k<<<1, 64, 0, stream>>>(gsum, gcnt, fc1w, fc1b, fc2w, fc2b, out);
}

// Round 7
// 391.938 us; speedup vs baseline: 2.7530x; 2.7530x over previous
//
#include <hip/hip_runtime.h>

#define N_NODES 100000
#define N_EDGES 1600000
#define N_GRAPHS_C 64
#define IN_F 86
#define H 64
#define N_BKT 391            // ceil(100000/256), bucket = dst >> 8
#define SC_EPT 8             // edges per thread in bucket passes
#define SC_TILE 2048         // 256 threads * 8
#define SC_GRID 782          // ceil(1.6M / 2048)
#define BC_GRID 860          // bn+count grid: 860*256 = 220160, divisible by 86
#define NW_POOL 2048         // waves in pool_k
typedef unsigned short ushort;

__device__ inline float bf2f(ushort u) { return __uint_as_float(((unsigned)u) << 16); }
__device__ inline ushort f2bf(float f) {
    unsigned x = __float_as_uint(f);
    return (ushort)((x + 0x7fffu + ((x >> 16) & 1u)) >> 16);  // RNE
}

// ---------------- fused: BN stats + per-bucket edge counts ----------------
__global__ void bn_count_k(const float* __restrict__ x, const int* __restrict__ dst,
                           float* __restrict__ bnsum, float* __restrict__ bnsq,
                           int* __restrict__ bcnt) {
    __shared__ float s1[IN_F], s2[IN_F];
    __shared__ int hist[N_BKT];
    int tid = threadIdx.x;
    if (tid < IN_F) { s1[tid] = 0.f; s2[tid] = 0.f; }
    for (int i = tid; i < N_BKT; i += 256) hist[i] = 0;
    __syncthreads();
    if (blockIdx.x < SC_GRID) {
        int e0 = blockIdx.x * SC_TILE;
#pragma unroll
        for (int i = 0; i < SC_EPT; i++) {
            int e = e0 + i * 256 + tid;
            if (e < N_EDGES) atomicAdd(&hist[dst[e] >> 8], 1);
        }
    }
    const int T = BC_GRID * 256;
    int t = blockIdx.x * 256 + tid;
    float sum = 0.f, sq = 0.f;
    for (int idx = t; idx < N_NODES * IN_F; idx += T) {
        float v = x[idx];
        sum += v; sq += v * v;
    }
    int f = t % IN_F;
    atomicAdd(&s1[f], sum);
    atomicAdd(&s2[f], sq);
    __syncthreads();
    if (tid < IN_F) {
        atomicAdd(&bnsum[tid], s1[tid]);
        atomicAdd(&bnsq[tid], s2[tid]);
    }
    if (blockIdx.x < SC_GRID)
        for (int i = tid; i < N_BKT; i += 256) atomicAdd(&bcnt[i], hist[i]);
}

// ---------------- fused: bucket scan + BN-fold prep ----------------
__global__ void scanprep_k(const int* __restrict__ bcnt, int* __restrict__ bstart,
                           int* __restrict__ gcursor,
                           const float* __restrict__ bnsum, const float* __restrict__ bnsq,
                           const float* __restrict__ gamma, const float* __restrict__ beta,
                           const float* __restrict__ W1, const float* __restrict__ b1,
                           float* __restrict__ W1p, float* __restrict__ c1) {
    __shared__ int tmp[512];
    __shared__ float scale[IN_F], shift[IN_F];
    int t = threadIdx.x;
    int v = (t < N_BKT) ? bcnt[t] : 0;
    tmp[t] = v;
    __syncthreads();
    for (int off = 1; off < 512; off <<= 1) {
        int a = (t >= off) ? tmp[t - off] : 0;
        __syncthreads();
        tmp[t] += a;
        __syncthreads();
    }
    if (t < N_BKT) { bstart[t] = tmp[t] - v; gcursor[t] = tmp[t] - v; }
    if (t == N_BKT - 1) bstart[N_BKT] = tmp[t];
    if (t < IN_F) {
        float mean = bnsum[t] * (1.0f / N_NODES);
        float var  = bnsq[t] * (1.0f / N_NODES) - mean * mean;
        float sc = gamma[t] * rsqrtf(var + 1e-5f);
        scale[t] = sc;
        shift[t] = beta[t] - mean * sc;
    }
    __syncthreads();
    for (int idx = t; idx < IN_F * H; idx += 512) W1p[idx] = scale[idx / H] * W1[idx];
    if (t < H) {
        float acc = b1[t];
        for (int i = 0; i < IN_F; i++) acc += shift[i] * W1[i * H + t];
        c1[t] = acc;
    }
}

// ---------------- CSR pass 1: partition edges (packed (src<<8)|dstLow) ----------------
__global__ void bucket_scatter_k(const int* __restrict__ src, const int* __restrict__ dst,
                                 int* __restrict__ gcursor, unsigned* __restrict__ ebkt) {
    __shared__ int hist[N_BKT];
    __shared__ int base[N_BKT];
    int tid = threadIdx.x;
    for (int i = tid; i < N_BKT; i += 256) hist[i] = 0;
    __syncthreads();
    int e0 = blockIdx.x * SC_TILE;
    unsigned pk[SC_EPT];
    int bk[SC_EPT], lo[SC_EPT];
#pragma unroll
    for (int i = 0; i < SC_EPT; i++) {
        int e = e0 + i * 256 + tid;
        if (e < N_EDGES) {
            int d = dst[e];
            pk[i] = ((unsigned)src[e] << 8) | (unsigned)(d & 255);
            bk[i] = d >> 8;
            lo[i] = atomicAdd(&hist[bk[i]], 1);
        }
    }
    __syncthreads();
    for (int i = tid; i < N_BKT; i += 256) base[i] = atomicAdd(&gcursor[i], hist[i]);
    __syncthreads();
#pragma unroll
    for (int i = 0; i < SC_EPT; i++) {
        int e = e0 + i * 256 + tid;
        if (e < N_EDGES) ebkt[base[bk[i]] + lo[i]] = pk[i];
    }
}

// ---------------- CSR pass 2: per-bucket degree+scan+fill ----------------
// rs[n] = INCLUSIVE end of node n's csr row. csr entries are BYTE offsets (src*128).
__global__ void bucket_fill_k(const unsigned* __restrict__ ebkt, const int* __restrict__ bstart,
                              int* __restrict__ rs, int* __restrict__ csr) {
    __shared__ int deg[256];
    __shared__ int scn[256];
    __shared__ int cur[256];
    int b = blockIdx.x;
    int tid = threadIdx.x;
    int e0 = bstart[b], e1 = bstart[b + 1];
    deg[tid] = 0;
    __syncthreads();
    for (int e = e0 + tid; e < e1; e += 256) atomicAdd(&deg[ebkt[e] & 255u], 1);
    __syncthreads();
    scn[tid] = deg[tid];
    __syncthreads();
    for (int off = 1; off < 256; off <<= 1) {
        int a = (tid >= off) ? scn[tid - off] : 0;
        __syncthreads();
        scn[tid] += a;
        __syncthreads();
    }
    int node = (b << 8) + tid;
    if (node < N_NODES) rs[node] = e0 + scn[tid];
    cur[tid] = e0 + scn[tid] - deg[tid];
    __syncthreads();
    for (int e = e0 + tid; e < e1; e += 256) {
        unsigned p = ebkt[e];
        int pos = atomicAdd(&cur[p & 255u], 1);
        csr[pos] = (int)((p & ~255u) >> 1);   // (src<<8)>>8<<7 = byte offset src*128
    }
}

// ---------------- GEMM (f32 in, K=86): Ybf16 = X @ W + bias ----------------
__global__ __launch_bounds__(256) void gemm_f32_k(const float* __restrict__ X,
                                                  const float* __restrict__ W,
                                                  const float* __restrict__ bias,
                                                  ushort* __restrict__ Y, int N) {
    const int K = IN_F;
    __shared__ __align__(16) float Xl[64][IN_F + 1];
    __shared__ __align__(16) float Wl[IN_F][64];
    int tid = threadIdx.x;
    int row0 = blockIdx.x * 64;
    for (int i = tid; i < K * 64; i += 256) Wl[i / 64][i % 64] = W[i];
    for (int i = tid; i < 64 * K; i += 256) {
        int r = i / K, c = i % K;
        Xl[r][c] = (row0 + r < N) ? X[(size_t)(row0 + r) * K + c] : 0.f;
    }
    __syncthreads();
    int cg = tid & 15, rg = tid >> 4;
    float4 b4 = *(const float4*)&bias[cg * 4];
    float acc[4][4];
    for (int i = 0; i < 4; i++) { acc[i][0] = b4.x; acc[i][1] = b4.y; acc[i][2] = b4.z; acc[i][3] = b4.w; }
    for (int k = 0; k < K; k++) {
        float4 w = *(const float4*)&Wl[k][cg * 4];
        float x0 = Xl[rg * 4 + 0][k];
        float x1 = Xl[rg * 4 + 1][k];
        float x2 = Xl[rg * 4 + 2][k];
        float x3 = Xl[rg * 4 + 3][k];
        acc[0][0] += x0 * w.x; acc[0][1] += x0 * w.y; acc[0][2] += x0 * w.z; acc[0][3] += x0 * w.w;
        acc[1][0] += x1 * w.x; acc[1][1] += x1 * w.y; acc[1][2] += x1 * w.z; acc[1][3] += x1 * w.w;
        acc[2][0] += x2 * w.x; acc[2][1] += x2 * w.y; acc[2][2] += x2 * w.z; acc[2][3] += x2 * w.w;
        acc[3][0] += x3 * w.x; acc[3][1] += x3 * w.y; acc[3][2] += x3 * w.z; acc[3][3] += x3 * w.w;
    }
    for (int i = 0; i < 4; i++) {
        int gr = row0 + rg * 4 + i;
        if (gr < N) {
            ushort4 o;
            o.x = f2bf(acc[i][0]); o.y = f2bf(acc[i][1]);
            o.z = f2bf(acc[i][2]); o.w = f2bf(acc[i][3]);
            *(ushort4*)&Y[(size_t)gr * 64 + cg * 4] = o;
        }
    }
}

// ---------------- GEMM (bf16 in, K=64): Ybf16 = X @ W + bias ----------------
__global__ __launch_bounds__(256) void gemm_bf16_k(const ushort* __restrict__ X,
                                                   const float* __restrict__ W,
                                                   const float* __restrict__ bias,
                                                   ushort* __restrict__ Y, int N) {
    const int K = H;
    __shared__ __align__(16) float Xl[64][H + 1];
    __shared__ __align__(16) float Wl[H][64];
    int tid = threadIdx.x;
    int row0 = blockIdx.x * 64;
    for (int i = tid; i < K * 64; i += 256) Wl[i / 64][i % 64] = W[i];
    for (int i = tid; i < 64 * 16; i += 256) {
        int r = i >> 4, c4 = (i & 15) * 4;
        if (row0 + r < N) {
            ushort4 u = *(const ushort4*)&X[(size_t)(row0 + r) * K + c4];
            Xl[r][c4 + 0] = bf2f(u.x); Xl[r][c4 + 1] = bf2f(u.y);
            Xl[r][c4 + 2] = bf2f(u.z); Xl[r][c4 + 3] = bf2f(u.w);
        } else {
            Xl[r][c4 + 0] = 0.f; Xl[r][c4 + 1] = 0.f;
            Xl[r][c4 + 2] = 0.f; Xl[r][c4 + 3] = 0.f;
        }
    }
    __syncthreads();
    int cg = tid & 15, rg = tid >> 4;
    float4 b4 = *(const float4*)&bias[cg * 4];
    float acc[4][4];
    for (int i = 0; i < 4; i++) { acc[i][0] = b4.x; acc[i][1] = b4.y; acc[i][2] = b4.z; acc[i][3] = b4.w; }
    for (int k = 0; k < K; k++) {
        float4 w = *(const float4*)&Wl[k][cg * 4];
        float x0 = Xl[rg * 4 + 0][k];
        float x1 = Xl[rg * 4 + 1][k];
        float x2 = Xl[rg * 4 + 2][k];
        float x3 = Xl[rg * 4 + 3][k];
        acc[0][0] += x0 * w.x; acc[0][1] += x0 * w.y; acc[0][2] += x0 * w.z; acc[0][3] += x0 * w.w;
        acc[1][0] += x1 * w.x; acc[1][1] += x1 * w.y; acc[1][2] += x1 * w.z; acc[1][3] += x1 * w.w;
        acc[2][0] += x2 * w.x; acc[2][1] += x2 * w.y; acc[2][2] += x2 * w.z; acc[2][3] += x2 * w.w;
        acc[3][0] += x3 * w.x; acc[3][1] += x3 * w.y; acc[3][2] += x3 * w.z; acc[3][3] += x3 * w.w;
    }
    for (int i = 0; i < 4; i++) {
        int gr = row0 + rg * 4 + i;
        if (gr < N) {
            ushort4 o;
            o.x = f2bf(acc[i][0]); o.y = f2bf(acc[i][1]);
            o.z = f2bf(acc[i][2]); o.w = f2bf(acc[i][3]);
            *(ushort4*)&Y[(size_t)gr * 64 + cg * 4] = o;
        }
    }
}

// ---------------- gather core: 8-deep unrolled mean-aggregate (csr = byte offsets) ----------------
__device__ inline float gather_row(const char* __restrict__ gB, const int* __restrict__ csr,
                                   int start, int end, int lane) {
    float a0 = 0.f, a1 = 0.f, a2 = 0.f, a3 = 0.f;
    float a4 = 0.f, a5 = 0.f, a6 = 0.f, a7 = 0.f;
    const char* gL = gB + (lane << 1);
    for (int j0 = start; j0 < end; j0 += 64) {
        int cnt = min(64, end - j0);
        int myoff = (lane < cnt) ? csr[j0 + lane] : 0;
        int j = 0;
        for (; j + 7 < cnt; j += 8) {
            int s0 = __shfl(myoff, j, 64);
            int s1 = __shfl(myoff, j + 1, 64);
            int s2 = __shfl(myoff, j + 2, 64);
            int s3 = __shfl(myoff, j + 3, 64);
            int s4 = __shfl(myoff, j + 4, 64);
            int s5 = __shfl(myoff, j + 5, 64);
            int s6 = __shfl(myoff, j + 6, 64);
            int s7 = __shfl(myoff, j + 7, 64);
            a0 += bf2f(*(const ushort*)(gL + s0));
            a1 += bf2f(*(const ushort*)(gL + s1));
            a2 += bf2f(*(const ushort*)(gL + s2));
            a3 += bf2f(*(const ushort*)(gL + s3));
            a4 += bf2f(*(const ushort*)(gL + s4));
            a5 += bf2f(*(const ushort*)(gL + s5));
            a6 += bf2f(*(const ushort*)(gL + s6));
            a7 += bf2f(*(const ushort*)(gL + s7));
        }
        for (; j + 3 < cnt; j += 4) {
            int s0 = __shfl(myoff, j, 64);
            int s1 = __shfl(myoff, j + 1, 64);
            int s2 = __shfl(myoff, j + 2, 64);
            int s3 = __shfl(myoff, j + 3, 64);
            a0 += bf2f(*(const ushort*)(gL + s0));
            a1 += bf2f(*(const ushort*)(gL + s1));
            a2 += bf2f(*(const ushort*)(gL + s2));
            a3 += bf2f(*(const ushort*)(gL + s3));
        }
        for (; j < cnt; j++) {
            int s = __shfl(myoff, j, 64);
            a0 += bf2f(*(const ushort*)(gL + s));
        }
    }
    return ((a0 + a1) + (a2 + a3)) + ((a4 + a5) + (a6 + a7));
}

// ---------------- gather1: h1[n] = relu(mean in-nbr g or g[n]) -> bf16 ----------------
__global__ void gather1_k(const ushort* __restrict__ g, const int* __restrict__ rs,
                          const int* __restrict__ csr, ushort* __restrict__ out) {
    int lane = threadIdx.x & 63;
    int n = blockIdx.x * 4 + (threadIdx.x >> 6);
    if (n >= N_NODES) return;
    int start = (n == 0) ? 0 : rs[n - 1];
    int end = rs[n];
    float acc = gather_row((const char*)g, csr, start, end, lane);
    int d = end - start;
    float val = (d > 0) ? acc / (float)d : bf2f(g[(size_t)n * H + lane]);
    out[(size_t)n * H + lane] = f2bf(fmaxf(val, 0.f));
}

// ---------------- pool: per-graph sums of bf16 h2 (graph_ids sorted, run-length) ----------------
__global__ void pool_k(const ushort* __restrict__ h, const int* __restrict__ gid,
                       float* __restrict__ gsum, int* __restrict__ gcnt) {
    int lane = threadIdx.x & 63;
    int wpb = blockDim.x >> 6;
    int gw = blockIdx.x * wpb + (threadIdx.x >> 6);
    const int chunk = (N_NODES + NW_POOL - 1) / NW_POOL;
    int n0 = gw * chunk;
    if (n0 >= N_NODES) return;
    int n1 = min(n0 + chunk, N_NODES);
    float acc = 0.f;
    int cur = gid[n0], cnt = 0;
    for (int n = n0; n < n1; n++) {
        int g = gid[n];
        if (g != cur) {
            atomicAdd(&gsum[cur * H + lane], acc);
            if (lane == 0) atomicAdd(&gcnt[cur], cnt);
            cur = g; acc = 0.f; cnt = 0;
        }
        acc += bf2f(h[(size_t)n * H + lane]);
        cnt++;
    }
    atomicAdd(&gsum[cur * H + lane], acc);
    if (lane == 0) atomicAdd(&gcnt[cur], cnt);
}

// ---------------- FC head + sigmoid (weights staged in LDS) ----------------
__global__ void head_k(const float* __restrict__ gsum, const int* __restrict__ gcnt,
                       const float* __restrict__ fc1w, const float* __restrict__ fc1b,
                       const float* __restrict__ fc2w, const float* __restrict__ fc2b,
                       float* __restrict__ out) {
    __shared__ float w1[H * 32];
    __shared__ float w2[32], bb1[32];
    int b = threadIdx.x;
    for (int i = b; i < H * 32; i += 64) w1[i] = fc1w[i];
    if (b < 32) { w2[b] = fc2w[b]; bb1[b] = fc1b[b]; }
    __syncthreads();
    if (b >= N_GRAPHS_C) return;
    float hg[H];
    float inv = 1.0f / fmaxf((float)gcnt[b], 1.0f);
    for (int k = 0; k < H; k++) hg[k] = gsum[b * H + k] * inv;
    float z = fc2b[0];
    for (int j = 0; j < 32; j++) {
        float t = bb1[j];
        for (int k = 0; k < H; k++) t += hg[k] * w1[k * 32 + j];
        z += t * w2[j];
    }
    out[b] = 1.0f / (1.0f + expf(-z));
}

extern "C" void kernel_launch(void* const* d_in, const int* in_sizes, int n_in,
                              void* d_out, int out_size, void* d_ws, size_t ws_size,
                              hipStream_t stream) {
    const float* x        = (const float*)d_in[0];
    const int*   edge_src = (const int*)d_in[1];
    const int*   edge_dst = (const int*)d_in[2];
    const int*   gid      = (const int*)d_in[3];
    const float* bn_gamma = (const float*)d_in[5];
    const float* bn_beta  = (const float*)d_in[6];
    const float* W1       = (const float*)d_in[7];
    const float* b1       = (const float*)d_in[8];
    const float* W2       = (const float*)d_in[9];
    const float* b2       = (const float*)d_in[10];
    const float* fc1w     = (const float*)d_in[11];
    const float* fc1b     = (const float*)d_in[12];
    const float* fc2w     = (const float*)d_in[13];
    const float* fc2b     = (const float*)d_in[14];
    float* out = (float*)d_out;

    // ---- workspace layout ----
    char* ws = (char*)d_ws;
    size_t off = 0;
    auto alloc = [&](size_t bytes) { void* p = ws + off; off += (bytes + 255) & ~(size_t)255; return p; };
    // zero-region: bnsum[86] bnsq[86] bcnt[391] gsum[4096] gcnt[64]  (one memset)
    const size_t ZW = IN_F + IN_F + N_BKT + N_GRAPHS_C * H + N_GRAPHS_C;
    float* zreg  = (float*)alloc(ZW * sizeof(float));
    float* bnsum = zreg;
    float* bnsq  = bnsum + IN_F;
    int*   bcnt  = (int*)(bnsq + IN_F);
    float* gsum  = (float*)(bcnt + N_BKT);
    int*   gcnt  = (int*)(gsum + N_GRAPHS_C * H);
    float* W1p     = (float*)alloc(IN_F * H * sizeof(float));
    float* c1      = (float*)alloc(H * sizeof(float));
    int*   bstart  = (int*)alloc((N_BKT + 1) * sizeof(int));
    int*   gcursor = (int*)alloc(N_BKT * sizeof(int));
    int*   rs      = (int*)alloc(N_NODES * sizeof(int));
    int*   csr     = (int*)alloc((size_t)N_EDGES * sizeof(int));
    ushort* gbuf   = (ushort*)alloc((size_t)N_NODES * H * sizeof(ushort));  // bf16 g1/g2 (12.8 MB)
    ushort* h1     = (ushort*)alloc((size_t)N_NODES * H * sizeof(ushort));  // bf16 h1, then h2 (12.8 MB)
    // ebkt (6.4 MB packed) aliases gbuf: consumed by bucket_fill_k BEFORE gemm writes gbuf.
    unsigned* ebkt = (unsigned*)gbuf;

    hipMemsetAsync(zreg, 0, ZW * sizeof(float), stream);

    // ---- fused BN stats + bucket counts ----
    bn_count_k<<<BC_GRID, 256, 0, stream>>>(x, edge_dst, bnsum, bnsq, bcnt);
    // ---- fused bucket scan + BN fold ----
    scanprep_k<<<1, 512, 0, stream>>>(bcnt, bstart, gcursor, bnsum, bnsq,
                                      bn_gamma, bn_beta, W1, b1, W1p, c1);
    // ---- CSR build ----
    bucket_scatter_k<<<SC_GRID, 256, 0, stream>>>(edge_src, edge_dst, gcursor, ebkt);
    bucket_fill_k<<<N_BKT, 256, 0, stream>>>(ebkt, bstart, rs, csr);

    // ---- layer 1 ----
    gemm_f32_k<<<(N_NODES + 63) / 64, 256, 0, stream>>>(x, W1p, c1, gbuf, N_NODES);
    gather1_k<<<(N_NODES + 3) / 4, 256, 0, stream>>>(gbuf, rs, csr, h1);

    // ---- layer 2 ----
    gemm_bf16_k<<<(N_NODES + 63) / 64, 256, 0, stream>>>(h1, W2, b2, gbuf, N_NODES);
    // gather2 writes h2 into the (now dead) h1 buffer
    gather1_k<<<(N_NODES + 3) / 4, 256, 0, stream>>>(gbuf, rs, csr, h1);

    // ---- pool + head ----
    pool_k<<<NW_POOL / 4, 256, 0, stream>>>(h1, gid, gsum, gcnt);
    head_k<<<1, 64, 0, stream>>>(gsum, gcnt, fc1w, fc1b, fc2w, fc2b, out);
}